// Round 9
// baseline (103.408 us; speedup 1.0000x reference)
//
#include <hip/hip_runtime.h>
#include <hip/hip_cooperative_groups.h>
#include <math.h>

// ConvCaps EM-routing, MI355X — cooperative fused kernel (grid-stride, runtime-
// sized grid, checked launch) with two-kernel fallback.
//
// Algebra: vv[n,ci,co,k] = Sv(n,ci,co>>1) * Wsum(sp=n%36,ci,co,k&3), so EM
// runs on a 32x32x4 table. EM: per group, 128 threads; wave wv owns
// o = wv*16+(lane&15), cq=lane>>4 owns 8 c's.

#define EPSF 1e-8f

typedef float f2 __attribute__((ext_vector_type(2)));

namespace cg = cooperative_groups;

// ================= shared EM body (group of 128 threads) =================
__device__ __forceinline__ void em_group(
        int n, int lt, float* Sv, float* avs, float* lgb,
        const float* __restrict__ bu, const float* __restrict__ ba,
        const float* __restrict__ S, const float* __restrict__ A,
        const float* __restrict__ Wsum, float* __restrict__ out) {
    const int wv = lt >> 6;
    const int lane = lt & 63;
    const int o = wv * 16 + (lane & 15);
    const int cq = lane >> 4;
    const int c0 = cq * 8;
    const int bq = n / 36;
    const int sp = n - bq * 36;

    if (lt < 32) avs[lt] = A[bq * 36 + (32 * sp + lt) % 36];
    for (int e = lt; e < 512; e += 128) {
        int ci = e >> 4, hc2 = e & 15;
        int B = sp * 32 + ci;
        int cc = B / 36;
        int rem = B - cc * 36;
        int off = cc * 576 + (rem / 6) * 96 + (rem % 6) * 16 + hc2;
        int hi = off / 1152;
        int lo = off - hi * 1152;
        Sv[e] = S[(bq * 16 + hi) * 36 + lo % 36];
    }
    __syncthreads();

    const int hc = o >> 1;
    f2 V2[8][2];
    float avr[8], r[8];
    const float* Wn = Wsum + sp * 4096;
#pragma unroll
    for (int cl = 0; cl < 8; ++cl) {
        int c = c0 + cl;
        float sv = Sv[c * 16 + hc];
        float4 w4 = *(const float4*)(Wn + c * 128 + o * 4);
        V2[cl][0] = (f2){sv * w4.x, sv * w4.y};
        V2[cl][1] = (f2){sv * w4.z, sv * w4.w};
        avr[cl] = avs[c];
        r[cl] = 0.03125f;
    }
    const float bu_o = bu[o];
    const float ba_o = ba[o];
    f2 mu2[2], q2[2];
    float aout = 0.f;
    const float lambdas[3] = {5.0e-4f, 9.75e-4f, 1.42625e-3f};

    for (int it = 0; it < 3; ++it) {
        float rp[8];
#pragma unroll
        for (int cl = 0; cl < 8; ++cl) rp[cl] = r[cl] * avr[cl] + EPSF;
        float rs = ((rp[0] + rp[1]) + (rp[2] + rp[3]))
                 + ((rp[4] + rp[5]) + (rp[6] + rp[7]));
        rs += __shfl_xor(rs, 16);
        rs += __shfl_xor(rs, 32);
        float rinv = 1.0f / rs;
#pragma unroll
        for (int p = 0; p < 2; ++p) {
            f2 a0 = {0.f, 0.f}, a1 = {0.f, 0.f};
#pragma unroll
            for (int cl = 0; cl < 8; cl += 2) {
                a0 += rp[cl] * V2[cl][p];
                a1 += rp[cl + 1] * V2[cl + 1][p];
            }
            f2 m = a0 + a1;
            m.x += __shfl_xor(m.x, 16); m.x += __shfl_xor(m.x, 32);
            m.y += __shfl_xor(m.y, 16); m.y += __shfl_xor(m.y, 32);
            mu2[p] = m * rinv;
        }
        float ls_sum;
        {
            float lsp[4];
#pragma unroll
            for (int p = 0; p < 2; ++p) {
                f2 a0 = {0.f, 0.f}, a1 = {0.f, 0.f};
#pragma unroll
                for (int cl = 0; cl < 8; cl += 2) {
                    f2 d0 = V2[cl][p] - mu2[p];
                    f2 d1 = V2[cl + 1][p] - mu2[p];
                    a0 += (d0 * d0) * rp[cl];
                    a1 += (d1 * d1) * rp[cl + 1];
                }
                f2 sg = a0 + a1;
                sg.x += __shfl_xor(sg.x, 16); sg.x += __shfl_xor(sg.x, 32);
                sg.y += __shfl_xor(sg.y, 16); sg.y += __shfl_xor(sg.y, 32);
                sg = sg * rinv + EPSF;
                lsp[2 * p]     = 0.5f * __logf(sg.x);
                lsp[2 * p + 1] = 0.5f * __logf(sg.y);
                q2[p] = (f2){2.0f / sg.x, 2.0f / sg.y};
            }
            ls_sum = (lsp[0] + lsp[1]) + (lsp[2] + lsp[3]);
        }
        float cost = (16.0f * bu_o + 4.0f * ls_sum) * rs;
        float z = lambdas[it] * (ba_o - cost);
        aout = 1.0f / (1.0f + __expf(-z));

        if (it < 2) {
            float T = __logf(aout) - 4.0f * ls_sum;
#pragma unroll
            for (int cl = 0; cl < 8; ++cl) {
                f2 d0 = V2[cl][0] - mu2[0];
                f2 d1 = V2[cl][1] - mu2[1];
                f2 s2 = (d0 * d0) * q2[0] + (d1 * d1) * q2[1];
                lgb[(c0 + cl) * 33 + o] = T - (s2.x + s2.y);
            }
            __syncthreads();
            {
                int cT = lt >> 2, q = lt & 3;
                float* rowp = &lgb[cT * 33 + q * 8];
                float4 u0 = *(float4*)(rowp);
                float4 u1 = *(float4*)(rowp + 4);
                float m0 = fmaxf(fmaxf(u0.x, u0.y), fmaxf(u0.z, u0.w));
                float m1 = fmaxf(fmaxf(u1.x, u1.y), fmaxf(u1.z, u1.w));
                float m = fmaxf(m0, m1);
                m = fmaxf(m, __shfl_xor(m, 1));
                m = fmaxf(m, __shfl_xor(m, 2));
                u0.x = __expf(u0.x - m); u0.y = __expf(u0.y - m);
                u0.z = __expf(u0.z - m); u0.w = __expf(u0.w - m);
                u1.x = __expf(u1.x - m); u1.y = __expf(u1.y - m);
                u1.z = __expf(u1.z - m); u1.w = __expf(u1.w - m);
                float s0 = (u0.x + u0.y) + (u0.z + u0.w);
                float s1 = (u1.x + u1.y) + (u1.z + u1.w);
                float ssum = s0 + s1;
                ssum += __shfl_xor(ssum, 1);
                ssum += __shfl_xor(ssum, 2);
                float inv = 1.0f / ssum;
                u0.x *= inv; u0.y *= inv; u0.z *= inv; u0.w *= inv;
                u1.x *= inv; u1.y *= inv; u1.z *= inv; u1.w *= inv;
                *(float4*)(rowp)     = u0;
                *(float4*)(rowp + 4) = u1;
            }
            __syncthreads();
#pragma unroll
            for (int cl = 0; cl < 8; ++cl)
                r[cl] = lgb[(c0 + cl) * 33 + o];
        }
    }

    float4 val = {mu2[0].x, mu2[0].y, mu2[1].x, mu2[1].y};
    float4* po = (float4*)(out + n * 512 + o * 16);
    po[cq] = val;
    if (cq == 0) out[1179648 + n * 32 + o] = aout;
}

// ================= fused cooperative kernel =================
__global__ __launch_bounds__(256, 4) void fused_kernel(
        const float* __restrict__ x, const float* __restrict__ a,
        const float* __restrict__ w, const float* __restrict__ bu,
        const float* __restrict__ ba, float* __restrict__ S,
        float* __restrict__ A, float* __restrict__ Wsum,
        float* __restrict__ out) {
    __shared__ float smem[6472];
    const int t = threadIdx.x;
    const int bid = blockIdx.x;
    const int nb = gridDim.x;

    for (int wi = bid * 256 + t; wi < 147456; wi += nb * 256) {
        int sp = wi >> 12;
        int rr = wi & 4095;
        int ci = rr >> 7, co = (rr >> 2) & 31, j = rr & 3;
        int B = sp * 32 + ci;
        int cc = B / 36;
        int rem = B - cc * 36;
        int wbase = cc * 18432 + (rem / 6) * 3072 + (rem % 6) * 512 + co * 16 + j;
        Wsum[wi] = w[wbase] + w[wbase + 4] + w[wbase + 8] + w[wbase + 12];
    }
    {
        float* plane = smem;
        float* bsum = smem + 6272;
        for (int p = bid; p < 1088; p += nb) {
            const float* src = (p < 1024) ? (x + (size_t)p * 6272)
                                          : (a + (size_t)(p - 1024) * 6272);
            for (int k = t; k < 1568; k += 256)
                *(float4*)&plane[k * 4] = *(const float4*)(src + k * 4);
            __syncthreads();
            if (t < 196) {
                float s = 0.f;
#pragma unroll
                for (int c = 0; c < 32; ++c) s += plane[c * 196 + t];
                bsum[t] = s;
            }
            __syncthreads();
            if (t < 36) {
                int oy = t / 6, ox = t - oy * 6;
                const float* q = &bsum[oy * 28 + ox * 2];
                float s = (q[0] + q[1] + q[2]) + (q[14] + q[15] + q[16])
                        + (q[28] + q[29] + q[30]);
                s *= (1.0f / 9.0f);
                if (p < 1024) S[p * 36 + t] = s;
                else          A[(p - 1024) * 36 + t] = s;
            }
            __syncthreads();
        }
    }

    cg::this_grid().sync();

    const int half = t >> 7;
    const int lt = t & 127;
    float* Sv = smem + half * 1600;
    for (int g2 = bid; g2 < 1152; g2 += nb) {
        em_group(g2 * 2 + half, lt, Sv, Sv + 512, Sv + 544,
                 bu, ba, S, A, Wsum, out);
        __syncthreads();
    }
}

// ================= fallback two-kernel path (R7, known-good) =================
__global__ __launch_bounds__(256) void pre_kernel(
        const float* __restrict__ x, const float* __restrict__ a,
        const float* __restrict__ w,
        float* __restrict__ S, float* __restrict__ A, float* __restrict__ Wsum) {
    int bid = blockIdx.x;
    if (bid < 1088) {
        __shared__ float plane[6272];
        __shared__ float bsum[196];
        const int t = threadIdx.x;
        const float* src = (bid < 1024) ? (x + (size_t)bid * 6272)
                                        : (a + (size_t)(bid - 1024) * 6272);
        for (int k = t; k < 1568; k += 256)
            *(float4*)&plane[k * 4] = *(const float4*)(src + k * 4);
        __syncthreads();
        if (t < 196) {
            float s = 0.f;
#pragma unroll
            for (int c = 0; c < 32; ++c) s += plane[c * 196 + t];
            bsum[t] = s;
        }
        __syncthreads();
        if (t < 36) {
            int oy = t / 6, ox = t - oy * 6;
            const float* q = &bsum[oy * 28 + ox * 2];
            float s = (q[0] + q[1] + q[2]) + (q[14] + q[15] + q[16])
                    + (q[28] + q[29] + q[30]);
            s *= (1.0f / 9.0f);
            if (bid < 1024) S[bid * 36 + t] = s;
            else            A[(bid - 1024) * 36 + t] = s;
        }
    } else {
        int wi = (bid - 1088) * 256 + threadIdx.x;
        int sp = wi >> 12;
        int rr = wi & 4095;
        int ci = rr >> 7, co = (rr >> 2) & 31, j = rr & 3;
        int B = sp * 32 + ci;
        int cc = B / 36;
        int rem = B - cc * 36;
        int wbase = cc * 18432 + (rem / 6) * 3072 + (rem % 6) * 512 + co * 16 + j;
        Wsum[wi] = w[wbase] + w[wbase + 4] + w[wbase + 8] + w[wbase + 12];
    }
}

__global__ __launch_bounds__(128, 4) void em_kernel(
        const float* __restrict__ bu, const float* __restrict__ ba,
        const float* __restrict__ S, const float* __restrict__ A,
        const float* __restrict__ Wsum, float* __restrict__ out) {
    __shared__ float Sv[1600];
    em_group(blockIdx.x, threadIdx.x, Sv, Sv + 512, Sv + 544,
             bu, ba, S, A, Wsum, out);
}

extern "C" void kernel_launch(void* const* d_in, const int* in_sizes, int n_in,
                              void* d_out, int out_size, void* d_ws, size_t ws_size,
                              hipStream_t stream) {
    const float* x = (const float*)d_in[0];
    const float* a = (const float*)d_in[1];
    const float* w = (const float*)d_in[2];
    const float* bu = (const float*)d_in[3];
    const float* ba = (const float*)d_in[4];
    float* out = (float*)d_out;

    float* S    = (float*)d_ws;          // 36864
    float* A    = S + 36864;             // 2304
    float* Wsum = A + 2304;              // 147456

    // Runtime-computed cooperative grid size (host-only query, capture-safe).
    int nbPerCU = 0;
    hipError_t qerr = hipOccupancyMaxActiveBlocksPerMultiprocessor(
        &nbPerCU, (const void*)fused_kernel, 256, 0);
    bool launched = false;
    if (qerr == hipSuccess && nbPerCU > 0) {
        int grid = nbPerCU * 256;            // 256 CUs on MI355X
        if (grid > 1152) grid = 1152;
        void* args[] = {(void*)&x, (void*)&a, (void*)&w, (void*)&bu, (void*)&ba,
                        (void*)&S, (void*)&A, (void*)&Wsum, (void*)&out};
        hipError_t lerr = hipLaunchCooperativeKernel(
            (const void*)fused_kernel, dim3(grid), dim3(256), args, 0, stream);
        launched = (lerr == hipSuccess);
    }
    if (!launched) {
        pre_kernel<<<1088 + 576, 256, 0, stream>>>(x, a, w, S, A, Wsum);
        em_kernel<<<2304, 128, 0, stream>>>(bu, ba, S, A, Wsum, out);
    }
}

// Round 10
// 28.286 us; speedup vs baseline: 3.6558x; 3.6558x over previous
//
#include <hip/hip_runtime.h>
#include <math.h>

// ConvCaps EM-routing, MI355X — two-kernel path: register-direct pre + 2-wave
// o-split EM (R7 em, unchanged).
//
// Algebra: vv[n,ci,co,k] = Sv(n,ci,co>>1) * Wsum(sp=n%36,ci,co,k&3), so EM
// runs on a 32x32x4 table. EM block = 128 threads (2 waves) per group.
// Wave wv owns o = wv*16+(lane&15); cq = lane>>4 owns c = cq*8..cq*8+7.

#define EPSF 1e-8f

typedef float f2 __attribute__((ext_vector_type(2)));

// ---- pre: box-filtered channel sums (S,A) + Wsum[36][32][32][4] ----
// bid < 1088: one plane per block. Thread t<196 owns hw position t and sums
// 32 channels with direct coalesced nontemporal loads (no LDS staging).
__global__ __launch_bounds__(256) void pre_kernel(
        const float* __restrict__ x, const float* __restrict__ a,
        const float* __restrict__ w,
        float* __restrict__ S, float* __restrict__ A, float* __restrict__ Wsum) {
    int bid = blockIdx.x;
    if (bid < 1088) {
        __shared__ float bsum[196];
        const int t = threadIdx.x;
        const float* src = (bid < 1024) ? (x + (size_t)bid * 6272)
                                        : (a + (size_t)(bid - 1024) * 6272);
        if (t < 196) {
            float s0 = 0.f, s1 = 0.f, s2 = 0.f, s3 = 0.f;
#pragma unroll
            for (int c = 0; c < 32; c += 4) {
                s0 += __builtin_nontemporal_load(src + (c + 0) * 196 + t);
                s1 += __builtin_nontemporal_load(src + (c + 1) * 196 + t);
                s2 += __builtin_nontemporal_load(src + (c + 2) * 196 + t);
                s3 += __builtin_nontemporal_load(src + (c + 3) * 196 + t);
            }
            bsum[t] = (s0 + s1) + (s2 + s3);
        }
        __syncthreads();
        if (t < 36) {
            int oy = t / 6, ox = t - oy * 6;
            const float* q = &bsum[oy * 28 + ox * 2];
            float s = (q[0] + q[1] + q[2]) + (q[14] + q[15] + q[16])
                    + (q[28] + q[29] + q[30]);
            s *= (1.0f / 9.0f);
            if (bid < 1024) S[bid * 36 + t] = s;
            else            A[(bid - 1024) * 36 + t] = s;
        }
    } else {
        int wi = (bid - 1088) * 256 + threadIdx.x;   // 147456 Wsum entries
        int sp = wi >> 12;
        int rr = wi & 4095;
        int ci = rr >> 7, co = (rr >> 2) & 31, j = rr & 3;
        int B = sp * 32 + ci;
        int cc = B / 36;
        int rem = B - cc * 36;
        int wbase = cc * 18432 + (rem / 6) * 3072 + (rem % 6) * 512 + co * 16 + j;
        Wsum[wi] = w[wbase] + w[wbase + 4] + w[wbase + 8] + w[wbase + 12];
    }
}

// ---- EM: one 128-thread block (2 waves) per routing group ----
__global__ __launch_bounds__(128, 4) void em_kernel(
        const float* __restrict__ bu, const float* __restrict__ ba,
        const float* __restrict__ S, const float* __restrict__ A,
        const float* __restrict__ Wsum, float* __restrict__ out) {
    __shared__ float Sv[512];
    __shared__ float avs[32];
    __shared__ float lgb[33 * 32];      // [c][o], stride 33

    const int t = threadIdx.x;
    const int w = t >> 6;
    const int lane = t & 63;
    const int o = w * 16 + (lane & 15); // owned output capsule
    const int cq = lane >> 4;           // c-quarter (0..3)
    const int c0 = cq * 8;
    const int n = blockIdx.x;
    const int bq = n / 36;
    const int sp = n - bq * 36;

    if (t < 32) avs[t] = A[bq * 36 + (32 * sp + t) % 36];
    for (int e = t; e < 512; e += 128) {
        int ci = e >> 4, hc2 = e & 15;
        int B = sp * 32 + ci;
        int cc = B / 36;
        int rem = B - cc * 36;
        int off = cc * 576 + (rem / 6) * 96 + (rem % 6) * 16 + hc2;
        int hi = off / 1152;
        int lo = off - hi * 1152;
        Sv[e] = S[(bq * 16 + hi) * 36 + lo % 36];
    }
    __syncthreads();

    const int hc = o >> 1;
    f2 V2[8][2];
    float avr[8], r[8];
    const float* Wn = Wsum + sp * 4096;
#pragma unroll
    for (int cl = 0; cl < 8; ++cl) {
        int c = c0 + cl;
        float sv = Sv[c * 16 + hc];
        float4 w4 = *(const float4*)(Wn + c * 128 + o * 4);
        V2[cl][0] = (f2){sv * w4.x, sv * w4.y};
        V2[cl][1] = (f2){sv * w4.z, sv * w4.w};
        avr[cl] = avs[c];
        r[cl] = 0.03125f;
    }
    const float bu_o = bu[o];
    const float ba_o = ba[o];
    f2 mu2[2], q2[2];
    float aout = 0.f;
    const float lambdas[3] = {5.0e-4f, 9.75e-4f, 1.42625e-3f};

    for (int it = 0; it < 3; ++it) {
        // ---- pass 1: rp, rs, mu (wave-local reduce over c) ----
        float rp[8];
#pragma unroll
        for (int cl = 0; cl < 8; ++cl) rp[cl] = r[cl] * avr[cl] + EPSF;
        float rs = ((rp[0] + rp[1]) + (rp[2] + rp[3]))
                 + ((rp[4] + rp[5]) + (rp[6] + rp[7]));
        rs += __shfl_xor(rs, 16);
        rs += __shfl_xor(rs, 32);
        float rinv = 1.0f / rs;
#pragma unroll
        for (int p = 0; p < 2; ++p) {
            f2 a0 = {0.f, 0.f}, a1 = {0.f, 0.f};
#pragma unroll
            for (int cl = 0; cl < 8; cl += 2) {
                a0 += rp[cl] * V2[cl][p];
                a1 += rp[cl + 1] * V2[cl + 1][p];
            }
            f2 m = a0 + a1;
            m.x += __shfl_xor(m.x, 16); m.x += __shfl_xor(m.x, 32);
            m.y += __shfl_xor(m.y, 16); m.y += __shfl_xor(m.y, 32);
            mu2[p] = m * rinv;
        }
        // ---- pass 2: sig (non-negative by construction) ----
        float ls_sum;
        {
            float lsp[4];
#pragma unroll
            for (int p = 0; p < 2; ++p) {
                f2 a0 = {0.f, 0.f}, a1 = {0.f, 0.f};
#pragma unroll
                for (int cl = 0; cl < 8; cl += 2) {
                    f2 d0 = V2[cl][p] - mu2[p];
                    f2 d1 = V2[cl + 1][p] - mu2[p];
                    a0 += (d0 * d0) * rp[cl];
                    a1 += (d1 * d1) * rp[cl + 1];
                }
                f2 sg = a0 + a1;
                sg.x += __shfl_xor(sg.x, 16); sg.x += __shfl_xor(sg.x, 32);
                sg.y += __shfl_xor(sg.y, 16); sg.y += __shfl_xor(sg.y, 32);
                sg = sg * rinv + EPSF;
                lsp[2 * p]     = 0.5f * __logf(sg.x);
                lsp[2 * p + 1] = 0.5f * __logf(sg.y);
                q2[p] = (f2){2.0f / sg.x, 2.0f / sg.y};
            }
            ls_sum = (lsp[0] + lsp[1]) + (lsp[2] + lsp[3]);
        }
        float cost = (16.0f * bu_o + 4.0f * ls_sum) * rs;
        float z = lambdas[it] * (ba_o - cost);
        aout = 1.0f / (1.0f + __expf(-z));

        if (it < 2) {
            // logits (softmax-invariant -8*log2pi dropped)
            float T = __logf(aout) - 4.0f * ls_sum;
#pragma unroll
            for (int cl = 0; cl < 8; ++cl) {
                f2 d0 = V2[cl][0] - mu2[0];
                f2 d1 = V2[cl][1] - mu2[1];
                f2 s2 = (d0 * d0) * q2[0] + (d1 * d1) * q2[1];
                lgb[(c0 + cl) * 33 + o] = T - (s2.x + s2.y);
            }
            __syncthreads();
            // transposed softmax: 128 lanes, lane = (c-row, quarter of o-row)
            {
                int cT = t >> 2, q = t & 3;
                float* rowp = &lgb[cT * 33 + q * 8];
                float4 u0 = *(float4*)(rowp);
                float4 u1 = *(float4*)(rowp + 4);
                float m0 = fmaxf(fmaxf(u0.x, u0.y), fmaxf(u0.z, u0.w));
                float m1 = fmaxf(fmaxf(u1.x, u1.y), fmaxf(u1.z, u1.w));
                float m = fmaxf(m0, m1);
                m = fmaxf(m, __shfl_xor(m, 1));
                m = fmaxf(m, __shfl_xor(m, 2));
                u0.x = __expf(u0.x - m); u0.y = __expf(u0.y - m);
                u0.z = __expf(u0.z - m); u0.w = __expf(u0.w - m);
                u1.x = __expf(u1.x - m); u1.y = __expf(u1.y - m);
                u1.z = __expf(u1.z - m); u1.w = __expf(u1.w - m);
                float s0 = (u0.x + u0.y) + (u0.z + u0.w);
                float s1 = (u1.x + u1.y) + (u1.z + u1.w);
                float ssum = s0 + s1;
                ssum += __shfl_xor(ssum, 1);
                ssum += __shfl_xor(ssum, 2);
                float inv = 1.0f / ssum;
                u0.x *= inv; u0.y *= inv; u0.z *= inv; u0.w *= inv;
                u1.x *= inv; u1.y *= inv; u1.z *= inv; u1.w *= inv;
                *(float4*)(rowp)     = u0;
                *(float4*)(rowp + 4) = u1;
            }
            __syncthreads();
#pragma unroll
            for (int cl = 0; cl < 8; ++cl)
                r[cl] = lgb[(c0 + cl) * 33 + o];
        }
    }

    // outputs: mu expanded to 16 k (k>>2 drops out); 4 cq-lanes hold identical
    // mu for their o — each writes one float4 quarter of the 16-k row.
    float4 val = {mu2[0].x, mu2[0].y, mu2[1].x, mu2[1].y};
    float4* po = (float4*)(out + n * 512 + o * 16);
    po[cq] = val;
    if (cq == 0) out[1179648 + n * 32 + o] = aout;
}

extern "C" void kernel_launch(void* const* d_in, const int* in_sizes, int n_in,
                              void* d_out, int out_size, void* d_ws, size_t ws_size,
                              hipStream_t stream) {
    const float* x = (const float*)d_in[0];
    const float* a = (const float*)d_in[1];
    const float* w = (const float*)d_in[2];
    const float* bu = (const float*)d_in[3];
    const float* ba = (const float*)d_in[4];
    float* out = (float*)d_out;

    float* S    = (float*)d_ws;          // 36864
    float* A    = S + 36864;             // 2304
    float* Wsum = A + 2304;              // 147456

    pre_kernel<<<1088 + 576, 256, 0, stream>>>(x, a, w, S, A, Wsum);
    em_kernel<<<2304, 128, 0, stream>>>(bu, ba, S, A, Wsum, out);
}